// Round 1
// baseline (203.006 us; speedup 1.0000x reference)
//
#include <hip/hip_runtime.h>
#include <math.h>

#define NB 8
#define KC 64
#define S1C 5
#define CC 128
#define PP 1936
#define MM (KC * S1C)      /* 320 */
#define PT 64
#define NPT 31             /* ceil(1936/64) */
#define ALPHAF 1500.0f
#define EPSF 1e-12f

/* ws layout (floats):
   accC [8][64][128] at 0        (65536)
   accS [8][64]      at 65536    (512)
   b    [320]        at 66048
   total 66368 floats = 265,472 B */
#define WS_ACCC 0
#define WS_ACCS (NB * KC * CC)
#define WS_B    (WS_ACCS + NB * KC)

// ---------------------------------------------------------------------------
// k0: b[m] = -ALPHA * ||centroids_row_m||  ; also zero the atomic accumulators
// ---------------------------------------------------------------------------
__global__ __launch_bounds__(64) void k0_prep(const float* __restrict__ cen,
                                              float* __restrict__ ws) {
    const int m = blockIdx.x;       // 0..319
    const int lane = threadIdx.x;   // 0..63
    // zero accC + accS (first WS_B floats)
    for (int i = m * 64 + lane; i < WS_B; i += MM * 64) ws[i] = 0.0f;
    const float* row = cen + m * CC;
    float v0 = row[lane];
    float v1 = row[lane + 64];
    float ss = v0 * v0 + v1 * v1;
#pragma unroll
    for (int off = 32; off > 0; off >>= 1) ss += __shfl_down(ss, off);
    if (lane == 0) ws[WS_B + m] = -ALPHAF * sqrtf(ss);
}

// ---------------------------------------------------------------------------
// k1: per (n, p-tile of 64): logits -> beta (regs) -> alpha -> soft_assign out
//     + partial C = sum_p (1+sa)*x via atomics, partial Swa via atomics
// ---------------------------------------------------------------------------
__global__ __launch_bounds__(256) void k1_main(
    const float* __restrict__ x, const float* __restrict__ cen,
    const float* __restrict__ ws, float* __restrict__ sa_out,
    float* __restrict__ accC, float* __restrict__ accS)
{
    __shared__ float xs[CC][68];   // pad 68: float4-aligned, 2-way max in both phases
    __shared__ float l0[KC][65];   // logits s=0, later reused as w_assign
    __shared__ float pmax[PT];
    __shared__ float prcs[PT];

    const int tid  = threadIdx.x;
    const int lane = tid & 63;
    const int wid  = tid >> 6;
    const int bx   = blockIdx.x;
    const int n    = bx / NPT;
    const int pt   = bx - n * NPT;
    const int p0   = pt * PT;

    // ---- stage x tile: xs[c][pp] = x[n][c][p0+pp] (zero-padded tail) ----
    const float* xn = x + (size_t)n * CC * PP;
    for (int idx = tid; idx < CC * 16; idx += 256) {
        const int c = idx >> 4;
        const int q = idx & 15;
        const int p = p0 + q * 4;
        float4 v = make_float4(0.f, 0.f, 0.f, 0.f);
        if (p < PP) v = *(const float4*)(xn + (size_t)c * PP + p);
        *(float4*)(&xs[c][q * 4]) = v;
    }
    __syncthreads();

    // ---- logits (5 per k) + beta kept in registers ----
    const float* bv = ws + WS_B;
    float beta_r[16];
#pragma unroll 1
    for (int i = 0; i < 16; ++i) {
        const int k = __builtin_amdgcn_readfirstlane(wid + 4 * i);  // wave-uniform
        const float4* w4 = (const float4*)(cen + (size_t)k * S1C * CC);
        float a0 = 0.f, a1 = 0.f, a2 = 0.f, a3 = 0.f, a4 = 0.f;
#pragma unroll 8
        for (int c4 = 0; c4 < 32; ++c4) {
            const float4 w0 = w4[c4];
            const float4 w1 = w4[32 + c4];
            const float4 w2 = w4[64 + c4];
            const float4 w3 = w4[96 + c4];
            const float4 w5 = w4[128 + c4];
            const float x0 = xs[4 * c4 + 0][lane];
            const float x1 = xs[4 * c4 + 1][lane];
            const float x2 = xs[4 * c4 + 2][lane];
            const float x3 = xs[4 * c4 + 3][lane];
            a0 += w0.x * x0 + w0.y * x1 + w0.z * x2 + w0.w * x3;
            a1 += w1.x * x0 + w1.y * x1 + w1.z * x2 + w1.w * x3;
            a2 += w2.x * x0 + w2.y * x1 + w2.z * x2 + w2.w * x3;
            a3 += w3.x * x0 + w3.y * x1 + w3.z * x2 + w3.w * x3;
            a4 += w5.x * x0 + w5.y * x1 + w5.z * x2 + w5.w * x3;
        }
        const float lg0 = 2.f * ALPHAF * a0 + bv[k * S1C + 0];
        const float lg1 = 2.f * ALPHAF * a1 + bv[k * S1C + 1];
        const float lg2 = 2.f * ALPHAF * a2 + bv[k * S1C + 2];
        const float lg3 = 2.f * ALPHAF * a3 + bv[k * S1C + 3];
        const float lg4 = 2.f * ALPHAF * a4 + bv[k * S1C + 4];
        const float m5 = fmaxf(fmaxf(fmaxf(lg0, lg1), fmaxf(lg2, lg3)), lg4);
        const float e0 = __expf(lg0 - m5);
        const float den = e0 + __expf(lg1 - m5) + __expf(lg2 - m5) +
                          __expf(lg3 - m5) + __expf(lg4 - m5);
        beta_r[i] = e0 / den;
        l0[k][lane] = lg0;
    }
    __syncthreads();

    // ---- alpha softmax over K per p (wave 0 only) ----
    if (tid < PT) {
        float mx = -3.0e38f;
        for (int k = 0; k < KC; ++k) mx = fmaxf(mx, l0[k][tid]);
        float s = 0.f;
        for (int k = 0; k < KC; ++k) s += __expf(l0[k][tid] - mx);
        pmax[tid] = mx;
        prcs[tid] = 1.0f / s;
    }
    __syncthreads();

    // ---- soft_assign out + w_assign into l0 (zero for pad p) ----
    const bool valid = (p0 + lane) < PP;
    float* san = sa_out + (size_t)n * KC * PP;
#pragma unroll 1
    for (int i = 0; i < 16; ++i) {
        const int k = wid + 4 * i;
        const float sa = __expf(l0[k][lane] - pmax[lane]) * prcs[lane] * beta_r[i];
        if (valid) san[(size_t)k * PP + p0 + lane] = sa;
        l0[k][lane] = valid ? (1.0f + sa) : 0.0f;
    }
    __syncthreads();

    // ---- partial C: acc[ki][j] += wa[k][p] * xs[c][p], 4k x 8c per thread ----
    const int c_blk = tid & 15;   // c = c_blk + 16*j  -> 16 distinct banks (pad 68)
    const int k_blk = tid >> 4;   // k = k_blk + 16*ki
    float acc[4][8];
#pragma unroll
    for (int a = 0; a < 4; ++a)
#pragma unroll
        for (int b = 0; b < 8; ++b) acc[a][b] = 0.f;

    for (int p = 0; p < PT; ++p) {
        const float wv0 = l0[k_blk +  0][p];
        const float wv1 = l0[k_blk + 16][p];
        const float wv2 = l0[k_blk + 32][p];
        const float wv3 = l0[k_blk + 48][p];
        float xv[8];
#pragma unroll
        for (int j = 0; j < 8; ++j) xv[j] = xs[c_blk + 16 * j][p];
#pragma unroll
        for (int j = 0; j < 8; ++j) {
            acc[0][j] += wv0 * xv[j];
            acc[1][j] += wv1 * xv[j];
            acc[2][j] += wv2 * xv[j];
            acc[3][j] += wv3 * xv[j];
        }
    }
    float* accCn = accC + (size_t)n * KC * CC;
#pragma unroll
    for (int ki = 0; ki < 4; ++ki)
#pragma unroll
        for (int j = 0; j < 8; ++j)
            atomicAdd(&accCn[(k_blk + 16 * ki) * CC + c_blk + 16 * j], acc[ki][j]);

    if (tid < KC) {
        float s = 0.f;
        for (int p = 0; p < PT; ++p) s += l0[tid][p];
        atomicAdd(&accS[n * KC + tid], s);
    }
}

// ---------------------------------------------------------------------------
// k2: out[n,k,c] = accC - rep[k,c]*Swa ; normalize over c ; /8 (flat norm)
// ---------------------------------------------------------------------------
__global__ __launch_bounds__(128) void k2_final(
    const float* __restrict__ accC, const float* __restrict__ accS,
    const float* __restrict__ cen, float* __restrict__ flat)
{
    __shared__ float w2[2];
    const int b = blockIdx.x;        // n*64 + k
    const int k = b & 63;
    const int c = threadIdx.x;       // 0..127
    const float v = accC[(size_t)b * CC + c] -
                    cen[(size_t)k * S1C * CC + c] * accS[b];
    float ss = v * v;
#pragma unroll
    for (int off = 32; off > 0; off >>= 1) ss += __shfl_down(ss, off);
    if ((c & 63) == 0) w2[c >> 6] = ss;
    __syncthreads();
    const float norm = sqrtf(w2[0] + w2[1]);
    // flat-level norm is exactly sqrt(64)=8 (every row normalized to 1, >> EPS)
    const float scale = 1.0f / (fmaxf(norm, EPSF) * 8.0f);
    flat[(size_t)b * CC + c] = v * scale;
}

// ---------------------------------------------------------------------------
extern "C" void kernel_launch(void* const* d_in, const int* in_sizes, int n_in,
                              void* d_out, int out_size, void* d_ws, size_t ws_size,
                              hipStream_t stream) {
    const float* x   = (const float*)d_in[0];   // [8][128][44][44]
    const float* cen = (const float*)d_in[1];   // [64][5][128]
    float* out  = (float*)d_out;
    float* flat = out;                           // [8][8192]
    float* sa   = out + (size_t)NB * KC * CC;    // [8][64][1][1936]
    float* ws   = (float*)d_ws;
    float* accC = ws + WS_ACCC;
    float* accS = ws + WS_ACCS;

    k0_prep<<<MM, 64, 0, stream>>>(cen, ws);
    k1_main<<<NB * NPT, 256, 0, stream>>>(x, cen, ws, sa, accC, accS);
    k2_final<<<NB * KC, 128, 0, stream>>>(accC, accS, cen, flat);
}

// Round 2
// 107.851 us; speedup vs baseline: 1.8823x; 1.8823x over previous
//
#include <hip/hip_runtime.h>
#include <math.h>

#define NB 8
#define KC 64
#define S1C 5
#define CC 128
#define PP 1936
#define MM (KC * S1C)      /* 320 */
#define PT 64
#define NPT 31             /* ceil(1936/64) */
#define ALPHAF 1500.0f
#define EPSF 1e-12f

/* ws layout (floats): accC [8][64][128] at 0 (65536) ; accS [8][64] at 65536 (512) */
#define WS_ACCC 0
#define WS_ACCS (NB * KC * CC)
#define WS_ZERO_BYTES ((size_t)(NB * KC * CC + NB * KC) * 4)

// ---------------------------------------------------------------------------
// k1: per (n, p-tile of 64), 1024 threads = 16 waves:
//   bias -> logits -> beta (regs) -> alpha softmax -> soft_assign out
//   -> partial C = sum_p (1+sa)*x via atomics, partial Swa via atomics
// ---------------------------------------------------------------------------
__global__ __launch_bounds__(1024) void k1_main(
    const float* __restrict__ x, const float* __restrict__ cen,
    float* __restrict__ sa_out, float* __restrict__ accC,
    float* __restrict__ accS)
{
    __shared__ float xs[CC][68];   // pad 68: 2-way max conflict in all phases (free)
    __shared__ float l0[KC][65];   // logits s=0, later reused as w_assign
    __shared__ float bias[MM];
    __shared__ float pmax[PT];
    __shared__ float prcs[PT];

    const int tid  = threadIdx.x;
    const int lane = tid & 63;
    const int wid  = tid >> 6;      // 0..15
    const int bx   = blockIdx.x;
    const int n    = bx / NPT;
    const int pt   = bx - n * NPT;
    const int p0   = pt * PT;

    // ---- stage x tile: xs[c][pp] = x[n][c][p0+pp] (zero-padded tail) ----
    const float* xn = x + (size_t)n * CC * PP;
    for (int idx = tid; idx < CC * 16; idx += 1024) {
        const int c = idx >> 4;
        const int q = idx & 15;
        const int p = p0 + q * 4;
        float4 v = make_float4(0.f, 0.f, 0.f, 0.f);
        if (p < PP) v = *(const float4*)(xn + (size_t)c * PP + p);  // PP%4==0: safe
        *(float4*)(&xs[c][q * 4]) = v;
    }
    // ---- bias: b[m] = -ALPHA * ||cen_m|| (threads 0..319, overlaps staging) ----
    if (tid < MM) {
        const float4* row = (const float4*)(cen + (size_t)tid * CC);
        float ss = 0.f;
#pragma unroll
        for (int c4 = 0; c4 < 32; ++c4) {
            const float4 v = row[c4];
            ss += v.x * v.x + v.y * v.y + v.z * v.z + v.w * v.w;
        }
        bias[tid] = -ALPHAF * sqrtf(ss);
    }
    __syncthreads();

    // ---- logits (5 per k) + beta kept in registers; wave handles k=wid+16i ----
    float beta_r[4];
#pragma unroll 1
    for (int i = 0; i < 4; ++i) {
        const int k = __builtin_amdgcn_readfirstlane(wid + 16 * i);  // wave-uniform
        const float4* w4 = (const float4*)(cen + (size_t)k * S1C * CC);
        float a0 = 0.f, a1 = 0.f, a2 = 0.f, a3 = 0.f, a4 = 0.f;
#pragma unroll 8
        for (int c4 = 0; c4 < 32; ++c4) {
            const float4 w0 = w4[c4];
            const float4 w1 = w4[32 + c4];
            const float4 w2 = w4[64 + c4];
            const float4 w3 = w4[96 + c4];
            const float4 w5 = w4[128 + c4];
            const float x0 = xs[4 * c4 + 0][lane];
            const float x1 = xs[4 * c4 + 1][lane];
            const float x2 = xs[4 * c4 + 2][lane];
            const float x3 = xs[4 * c4 + 3][lane];
            a0 += w0.x * x0 + w0.y * x1 + w0.z * x2 + w0.w * x3;
            a1 += w1.x * x0 + w1.y * x1 + w1.z * x2 + w1.w * x3;
            a2 += w2.x * x0 + w2.y * x1 + w2.z * x2 + w2.w * x3;
            a3 += w3.x * x0 + w3.y * x1 + w3.z * x2 + w3.w * x3;
            a4 += w5.x * x0 + w5.y * x1 + w5.z * x2 + w5.w * x3;
        }
        const float lg0 = 2.f * ALPHAF * a0 + bias[k * S1C + 0];
        const float lg1 = 2.f * ALPHAF * a1 + bias[k * S1C + 1];
        const float lg2 = 2.f * ALPHAF * a2 + bias[k * S1C + 2];
        const float lg3 = 2.f * ALPHAF * a3 + bias[k * S1C + 3];
        const float lg4 = 2.f * ALPHAF * a4 + bias[k * S1C + 4];
        const float m5 = fmaxf(fmaxf(fmaxf(lg0, lg1), fmaxf(lg2, lg3)), lg4);
        const float e0 = __expf(lg0 - m5);
        const float den = e0 + __expf(lg1 - m5) + __expf(lg2 - m5) +
                          __expf(lg3 - m5) + __expf(lg4 - m5);
        beta_r[i] = e0 / den;
        l0[k][lane] = lg0;
    }
    __syncthreads();

    // ---- alpha softmax over K per p (threads 0..63) ----
    if (tid < PT) {
        float mx = -3.0e38f;
        for (int k = 0; k < KC; ++k) mx = fmaxf(mx, l0[k][tid]);
        float s = 0.f;
        for (int k = 0; k < KC; ++k) s += __expf(l0[k][tid] - mx);
        pmax[tid] = mx;
        prcs[tid] = 1.0f / s;
    }
    __syncthreads();

    // ---- soft_assign out + w_assign into l0 (zero for pad p) ----
    const bool valid = (p0 + lane) < PP;
    float* san = sa_out + (size_t)n * KC * PP;
#pragma unroll 1
    for (int i = 0; i < 4; ++i) {
        const int k = wid + 16 * i;
        const float sa = __expf(l0[k][lane] - pmax[lane]) * prcs[lane] * beta_r[i];
        if (valid) san[(size_t)k * PP + p0 + lane] = sa;
        l0[k][lane] = valid ? (1.0f + sa) : 0.0f;
    }
    __syncthreads();

    // ---- partial C: each thread 1 k x 8 c ----
    const int c_blk = tid & 15;
    const int k     = tid >> 4;     // 0..63
    float acc[8];
#pragma unroll
    for (int j = 0; j < 8; ++j) acc[j] = 0.f;

    for (int p = 0; p < PT; ++p) {
        const float wv = l0[k][p];
#pragma unroll
        for (int j = 0; j < 8; ++j) acc[j] += wv * xs[c_blk + 16 * j][p];
    }
    float* accCn = accC + (size_t)n * KC * CC;
#pragma unroll
    for (int j = 0; j < 8; ++j)
        atomicAdd(&accCn[k * CC + c_blk + 16 * j], acc[j]);

    if (tid < KC) {
        float s = 0.f;
        for (int p = 0; p < PT; ++p) s += l0[tid][p];
        atomicAdd(&accS[n * KC + tid], s);
    }
}

// ---------------------------------------------------------------------------
// k2: out[n,k,c] = accC - rep[k,c]*Swa ; normalize over c ; /8 (flat norm)
// ---------------------------------------------------------------------------
__global__ __launch_bounds__(128) void k2_final(
    const float* __restrict__ accC, const float* __restrict__ accS,
    const float* __restrict__ cen, float* __restrict__ flat)
{
    __shared__ float w2[2];
    const int b = blockIdx.x;        // n*64 + k
    const int k = b & 63;
    const int c = threadIdx.x;       // 0..127
    const float v = accC[(size_t)b * CC + c] -
                    cen[(size_t)k * S1C * CC + c] * accS[b];
    float ss = v * v;
#pragma unroll
    for (int off = 32; off > 0; off >>= 1) ss += __shfl_down(ss, off);
    if ((c & 63) == 0) w2[c >> 6] = ss;
    __syncthreads();
    const float norm = sqrtf(w2[0] + w2[1]);
    // flat-level norm is exactly sqrt(64)=8 (every row unit-norm, >> EPS)
    const float scale = 1.0f / (fmaxf(norm, EPSF) * 8.0f);
    flat[(size_t)b * CC + c] = v * scale;
}

// ---------------------------------------------------------------------------
extern "C" void kernel_launch(void* const* d_in, const int* in_sizes, int n_in,
                              void* d_out, int out_size, void* d_ws, size_t ws_size,
                              hipStream_t stream) {
    const float* x   = (const float*)d_in[0];   // [8][128][44][44]
    const float* cen = (const float*)d_in[1];   // [64][5][128]
    float* out  = (float*)d_out;
    float* flat = out;                           // [8][8192]
    float* sa   = out + (size_t)NB * KC * CC;    // [8][64][1][1936]
    float* ws   = (float*)d_ws;
    float* accC = ws + WS_ACCC;
    float* accS = ws + WS_ACCS;

    hipMemsetAsync(d_ws, 0, WS_ZERO_BYTES, stream);
    k1_main<<<NB * NPT, 1024, 0, stream>>>(x, cen, sa, accC, accS);
    k2_final<<<NB * KC, 128, 0, stream>>>(accC, accS, cen, flat);
}